// Round 1
// baseline (281.772 us; speedup 1.0000x reference)
//
#include <hip/hip_runtime.h>
#include <cstdint>
#include <cstddef>

typedef unsigned short u16;
typedef __attribute__((ext_vector_type(8))) short bf16x8;   // 8 bf16 (4 VGPR) MFMA frag
typedef __attribute__((ext_vector_type(8))) u16   u16x8;
typedef __attribute__((ext_vector_type(4))) short short4v;
typedef __attribute__((ext_vector_type(4))) float f32x4;

#define DEVI static __device__ __forceinline__

constexpr int B_   = 2;
constexpr int S_   = 2048;
constexpr int HID_ = 2048;
constexpr int NH_  = 16;
constexpr int NKV_ = 4;
constexpr int HD_  = 128;
constexpr int TOK  = B_ * S_;              // 4096
constexpr int OQKV = (NH_ + 2*NKV_) * HD_; // 3072

DEVI u16 f2bf(float f) {                  // RNE f32->bf16 (finite inputs)
  uint32_t u = __builtin_bit_cast(uint32_t, f);
  return (u16)((u + 0x7fffu + ((u >> 16) & 1u)) >> 16);
}
DEVI float bf2f(u16 h) { return __builtin_bit_cast(float, (uint32_t)h << 16); }

DEVI void gll16(const void* g, void* l) { // 16B global -> LDS direct
  __builtin_amdgcn_global_load_lds(
      (const __attribute__((address_space(1))) uint32_t*)g,
      (__attribute__((address_space(3))) uint32_t*)l, 16, 0, 0);
}

// ---------------- f32 -> bf16 convert, 8 elems/thread ----------------
__global__ __launch_bounds__(256) void cvt_kernel(const float* __restrict__ in,
                                                  u16* __restrict__ out, int n8) {
  int idx = blockIdx.x * 256 + threadIdx.x;
  int stride = gridDim.x * 256;
  for (int i = idx; i < n8; i += stride) {
    const float4* p = reinterpret_cast<const float4*>(in) + (size_t)i * 2;
    float4 a = p[0], b = p[1];
    u16x8 v;
    v[0] = f2bf(a.x); v[1] = f2bf(a.y); v[2] = f2bf(a.z); v[3] = f2bf(a.w);
    v[4] = f2bf(b.x); v[5] = f2bf(b.y); v[6] = f2bf(b.z); v[7] = f2bf(b.w);
    reinterpret_cast<u16x8*>(out)[i] = v;
  }
}

// ---------------- C[m,n] = sum_k A[m,k] * B[n,k]  (both row-major, bf16) ---
// 128x128 tile, BK=32, 4 waves (2x2 of 64x64), 16x16x32 bf16 MFMA,
// global_load_lds staging, double-buffered LDS (T3 minimal 2-phase).
template <bool OUT_BF16>
__global__ __launch_bounds__(256) void gemm_bt_kernel(
    const u16* __restrict__ A, const u16* __restrict__ B, void* __restrict__ Cv,
    int M, int N, int K) {
  constexpr int BM = 128, BN = 128, BK = 32;
  __shared__ __align__(16) u16 As[2][BM * BK];
  __shared__ __align__(16) u16 Bs[2][BN * BK];
  const int tid  = threadIdx.x;
  const int lane = tid & 63;
  const int wid  = tid >> 6;
  const int bm = blockIdx.x * BM;
  const int bn = blockIdx.y * BN;
  const int wm = (wid >> 1) * 64;
  const int wn = (wid & 1) * 64;
  const int fr = lane & 15, fg = lane >> 4;

  const f32x4 fzero = {0.f, 0.f, 0.f, 0.f};
  f32x4 acc[4][4];
#pragma unroll
  for (int m = 0; m < 4; m++)
#pragma unroll
    for (int n = 0; n < 4; n++) acc[m][n] = fzero;

  auto stage = [&](int buf, int k0) {
#pragma unroll
    for (int i = 0; i < 2; i++) {
      int e = i * 256 + tid;  // 8-elem group: row e>>2, col (e&3)*8
      gll16(A + (size_t)(bm + (e >> 2)) * K + (k0 + (e & 3) * 8), &As[buf][e * 8]);
    }
#pragma unroll
    for (int i = 0; i < 2; i++) {
      int e = i * 256 + tid;
      gll16(B + (size_t)(bn + (e >> 2)) * K + (k0 + (e & 3) * 8), &Bs[buf][e * 8]);
    }
  };

  stage(0, 0);
  __syncthreads();  // compiler drains vmcnt(0) before s_barrier
  const int nt = K / BK;
  for (int t = 0; t < nt; ++t) {
    int cur = t & 1;
    if (t + 1 < nt) stage(cur ^ 1, (t + 1) * BK);
    bf16x8 af[4], bfv[4];
#pragma unroll
    for (int m = 0; m < 4; m++)
      af[m] = *reinterpret_cast<const bf16x8*>(&As[cur][(wm + m * 16 + fr) * BK + fg * 8]);
#pragma unroll
    for (int n = 0; n < 4; n++)
      bfv[n] = *reinterpret_cast<const bf16x8*>(&Bs[cur][(wn + n * 16 + fr) * BK + fg * 8]);
#pragma unroll
    for (int m = 0; m < 4; m++)
#pragma unroll
      for (int n = 0; n < 4; n++)
        acc[m][n] = __builtin_amdgcn_mfma_f32_16x16x32_bf16(af[m], bfv[n], acc[m][n], 0, 0, 0);
    __syncthreads();
  }

  // C/D layout: col = lane&15, row = (lane>>4)*4 + j   [m89-verified]
#pragma unroll
  for (int m = 0; m < 4; m++)
#pragma unroll
    for (int n = 0; n < 4; n++)
#pragma unroll
      for (int j = 0; j < 4; j++) {
        size_t row = bm + wm + m * 16 + fg * 4 + j;
        size_t col = bn + wn + n * 16 + fr;
        if constexpr (OUT_BF16)
          reinterpret_cast<u16*>(Cv)[row * N + col] = f2bf(acc[m][n][j]);
        else
          reinterpret_cast<float*>(Cv)[row * N + col] = acc[m][n][j];
      }
}

// ---------------- fused RMSNorm + RoPE; one wave per (token, head-slot) ----
// slots 0..15 = Q heads, 16..19 = K heads. lane l owns dims {l, l+64}.
__global__ __launch_bounds__(256) void rmsrope_kernel(
    const u16* __restrict__ qkv, const float* __restrict__ cosb,
    const float* __restrict__ sinb, const float* __restrict__ qw,
    const float* __restrict__ kw, u16* __restrict__ Q, u16* __restrict__ K) {
  int gw   = blockIdx.x * 4 + (threadIdx.x >> 6);
  int lane = threadIdx.x & 63;
  int tok  = gw / 20;
  int slot = gw - tok * 20;
  if (tok >= TOK) return;
  int b = tok >> 11, s = tok & (S_ - 1);
  const u16* src = qkv + (size_t)tok * OQKV + slot * HD_;
  float x0 = bf2f(src[lane]);
  float x1 = bf2f(src[lane + 64]);
  float ss = x0 * x0 + x1 * x1;
#pragma unroll
  for (int m = 1; m < 64; m <<= 1) ss += __shfl_xor(ss, m, 64);
  float r = rsqrtf(ss * (1.0f / 128.0f) + 1e-6f);
  const float* w = (slot < 16) ? qw : kw;
  x0 *= r * w[lane];
  x1 *= r * w[lane + 64];
  // RoPE on dims 0..63 (x0 only): rot[d] = (d<32 ? -x[d+32] : x[d-32])
  float c  = cosb[(size_t)tok * 64 + lane];
  float sn = sinb[(size_t)tok * 64 + lane];
  float partner = __shfl_xor(x0, 32, 64);
  float rot = (lane < 32) ? -partner : partner;
  x0 = x0 * c + rot * sn;
  u16* dst;
  if (slot < 16) dst = Q + (((size_t)b * NH_ + slot) * S_ + s) * HD_;
  else           dst = K + (((size_t)b * NKV_ + (slot - 16)) * S_ + s) * HD_;
  dst[lane]      = f2bf(x0);
  dst[lane + 64] = f2bf(x1);
}

// ---------------- flash attention (non-causal, GQA), exp-sum softmax -------
// |score| <= sqrt(128) ~= 11.3 after RMSNorm => no max subtraction needed.
// Block = 4 waves x 16 q-rows (QBLK=64), KVBLK=64.
// Ksm [64][128] XOR-swizzled; Vt = V^T [128][64] XOR-swizzled; P via
// per-wave LDS bounce (D-layout -> A-layout).
__global__ __launch_bounds__(256) void attn_kernel(
    const u16* __restrict__ Q, const u16* __restrict__ K,
    const u16* __restrict__ QKVb, u16* __restrict__ O) {
  __shared__ __align__(16) u16 Ksm[64 * 128];
  __shared__ __align__(16) u16 Vt[128 * 64];
  __shared__ __align__(16) u16 Psm[4][16 * 72];
  const int tid = threadIdx.x;
  const int lane = tid & 63, wid = tid >> 6;
  const int fr = lane & 15, fg = lane >> 4;
  const int qt = blockIdx.x, bh = blockIdx.y;
  const int b = bh >> 4, h = bh & 15, kvh = h >> 2;

  const u16* Qbase = Q + ((size_t)b * NH_ + h) * S_ * HD_;
  const u16* Kbase = K + ((size_t)b * NKV_ + kvh) * S_ * HD_;
  const u16* Vbase = QKVb + (size_t)b * S_ * OQKV + (NH_ + NKV_) * HD_ + kvh * HD_;

  bf16x8 qf[4];
  {
    const u16* qp = Qbase + (size_t)(qt * 64 + wid * 16 + fr) * HD_ + fg * 8;
#pragma unroll
    for (int c = 0; c < 4; c++) qf[c] = *reinterpret_cast<const bf16x8*>(qp + c * 32);
  }

  const f32x4 fzero = {0.f, 0.f, 0.f, 0.f};
  f32x4 acc[8];
#pragma unroll
  for (int i = 0; i < 8; i++) acc[i] = fzero;
  float rs[4] = {0.f, 0.f, 0.f, 0.f};
  const float scale = 0.08838834764831845f;  // 1/sqrt(128)

  for (int kt = 0; kt < S_ / 64; ++kt) {
    __syncthreads();  // previous iter's LDS reads done before overwrite
    {  // stage K, swizzled: byte ^= (row&7)<<4
      const u16* Kt = Kbase + (size_t)kt * 64 * HD_;
#pragma unroll
      for (int i = 0; i < 4; i++) {
        int e = i * 256 + tid;
        int krow = e >> 4, kc = e & 15;
        bf16x8 kv8 = *reinterpret_cast<const bf16x8*>(Kt + (size_t)krow * HD_ + kc * 8);
        int off = (krow * 256 + kc * 16) ^ ((krow & 7) << 4);
        *reinterpret_cast<bf16x8*>(reinterpret_cast<char*>(Ksm) + off) = kv8;
      }
    }
    {  // stage V transposed + swizzled: row d, byte ^= (((d&7)^((d>>3)&7))<<4)
      const u16* Vtile = Vbase + (size_t)(kt * 64) * OQKV;
      int kvb = tid >> 4, db = tid & 15;
      bf16x8 vr[4];
#pragma unroll
      for (int i = 0; i < 4; i++)
        vr[i] = *reinterpret_cast<const bf16x8*>(Vtile + (size_t)(kvb * 4 + i) * OQKV + db * 8);
#pragma unroll
      for (int j = 0; j < 8; j++) {
        int d = db * 8 + j;
        int off = (d * 128 + kvb * 8) ^ ((((d & 7) ^ ((d >> 3) & 7))) << 4);
        short4v wv = {vr[0][j], vr[1][j], vr[2][j], vr[3][j]};
        *reinterpret_cast<short4v*>(reinterpret_cast<char*>(Vt) + off) = wv;
      }
    }
    __syncthreads();

    // QK^T -> exp -> P (D-layout: row q=(fg*4+j), col kv=nf*16+fr)
    u16 pb[4][4];
#pragma unroll
    for (int nf = 0; nf < 4; nf++) {
      f32x4 sacc = fzero;
      int krow = nf * 16 + fr;
#pragma unroll
      for (int c = 0; c < 4; c++) {
        int off = (krow * 256 + c * 64 + fg * 16) ^ ((krow & 7) << 4);
        bf16x8 kf = *reinterpret_cast<const bf16x8*>(reinterpret_cast<const char*>(Ksm) + off);
        sacc = __builtin_amdgcn_mfma_f32_16x16x32_bf16(qf[c], kf, sacc, 0, 0, 0);
      }
#pragma unroll
      for (int j = 0; j < 4; j++) {
        float p = __expf(sacc[j] * scale);
        rs[j] += p;
        pb[nf][j] = f2bf(p);
      }
    }
    // P: D-layout -> A-layout via per-wave LDS (no barrier needed)
#pragma unroll
    for (int nf = 0; nf < 4; nf++)
#pragma unroll
      for (int j = 0; j < 4; j++)
        Psm[wid][(fg * 4 + j) * 72 + nf * 16 + fr] = pb[nf][j];
    asm volatile("s_waitcnt lgkmcnt(0)" ::: "memory");
    bf16x8 pf[2];
#pragma unroll
    for (int c = 0; c < 2; c++)
      pf[c] = *reinterpret_cast<const bf16x8*>(&Psm[wid][fr * 72 + c * 32 + fg * 8]);
    // PV: acc[nf] over d = nf*16 + (lane&15)
#pragma unroll
    for (int nf = 0; nf < 8; nf++) {
      int d = nf * 16 + fr;
      int swz = (((d & 7) ^ ((d >> 3) & 7)) << 4);
#pragma unroll
      for (int c = 0; c < 2; c++) {
        int off = (d * 128 + c * 64 + fg * 16) ^ swz;
        bf16x8 vf = *reinterpret_cast<const bf16x8*>(reinterpret_cast<const char*>(Vt) + off);
        acc[nf] = __builtin_amdgcn_mfma_f32_16x16x32_bf16(pf[c], vf, acc[nf], 0, 0, 0);
      }
    }
  }

  // row-sum reduce across the 16 lanes holding each q-row, then write O
#pragma unroll
  for (int j = 0; j < 4; j++) {
    float v = rs[j];
    v += __shfl_xor(v, 1, 64);
    v += __shfl_xor(v, 2, 64);
    v += __shfl_xor(v, 4, 64);
    v += __shfl_xor(v, 8, 64);
    rs[j] = 1.0f / v;
  }
  const int qrow0 = qt * 64 + wid * 16 + fg * 4;
  u16* ob = O + ((size_t)b * S_ + qrow0) * HID_ + h * HD_;
#pragma unroll
  for (int nf = 0; nf < 8; nf++)
#pragma unroll
    for (int j = 0; j < 4; j++)
      ob[(size_t)j * HID_ + nf * 16 + fr] = f2bf(acc[nf][j] * rs[j]);
}

// ---------------------------------------------------------------------------
extern "C" void kernel_launch(void* const* d_in, const int* in_sizes, int n_in,
                              void* d_out, int out_size, void* d_ws, size_t ws_size,
                              hipStream_t stream) {
  (void)in_sizes; (void)n_in; (void)out_size; (void)ws_size;
  const float* hs   = (const float*)d_in[0];
  const float* cosb = (const float*)d_in[1];
  const float* sinb = (const float*)d_in[2];
  const float* wqkv = (const float*)d_in[3];
  const float* qw   = (const float*)d_in[4];
  const float* kw   = (const float*)d_in[5];
  const float* wd   = (const float*)d_in[6];
  float* out = (float*)d_out;
  char* ws = (char*)d_ws;
  constexpr size_t MB = 1048576;
  u16* Xb    = (u16*)(ws + 0 * MB);    // 16 MB  X bf16        [4096][2048]
  u16* Wqkvb = (u16*)(ws + 16 * MB);   // 12 MB  w_qkv bf16    [3072][2048]
  u16* Wdb   = (u16*)(ws + 28 * MB);   //  8 MB  w_dense bf16  [2048][2048]
  u16* QKVb  = (u16*)(ws + 36 * MB);   // 24 MB  qkv bf16      [4096][3072]
  u16* Qb    = (u16*)(ws + 60 * MB);   // 16 MB  Q             [B][NH][S][HD]
  u16* Kb    = (u16*)(ws + 76 * MB);   //  4 MB  K             [B][NKV][S][HD]
  u16* Ob    = (u16*)(ws + 80 * MB);   // 16 MB  attn out      [B][S][NH*HD]

  cvt_kernel<<<2048, 256, 0, stream>>>(hs, Xb, TOK * HID_ / 8);
  cvt_kernel<<<2048, 256, 0, stream>>>(wqkv, Wqkvb, OQKV * HID_ / 8);
  cvt_kernel<<<1024, 256, 0, stream>>>(wd, Wdb, HID_ * HID_ / 8);

  gemm_bt_kernel<true><<<dim3(TOK / 128, OQKV / 128), 256, 0, stream>>>(
      Xb, Wqkvb, QKVb, TOK, OQKV, HID_);

  rmsrope_kernel<<<TOK * 20 / 4, 256, 0, stream>>>(QKVb, cosb, sinb, qw, kw, Qb, Kb);

  attn_kernel<<<dim3(S_ / 64, B_ * NH_), 256, 0, stream>>>(Qb, Kb, QKVb, Ob);

  gemm_bt_kernel<false><<<dim3(TOK / 128, HID_ / 128), 256, 0, stream>>>(
      Ob, Wdb, out, TOK, HID_, HID_);
}

// Round 4
// 227.490 us; speedup vs baseline: 1.2386x; 1.2386x over previous
//
#include <hip/hip_runtime.h>
#include <cstdint>
#include <cstddef>

typedef unsigned short u16;
typedef __attribute__((ext_vector_type(8))) short bf16x8;   // 8 bf16 (4 VGPR) MFMA frag
typedef __attribute__((ext_vector_type(8))) u16   u16x8;
typedef __attribute__((ext_vector_type(4))) short short4v;
typedef __attribute__((ext_vector_type(4))) float f32x4;
typedef __attribute__((ext_vector_type(16))) float f32x16;
typedef __attribute__((ext_vector_type(4))) unsigned int u32x4;

#define DEVI static __device__ __forceinline__

constexpr int B_   = 2;
constexpr int S_   = 2048;
constexpr int HID_ = 2048;
constexpr int NH_  = 16;
constexpr int NKV_ = 4;
constexpr int HD_  = 128;
constexpr int TOK  = B_ * S_;              // 4096
constexpr int OQKV = (NH_ + 2*NKV_) * HD_; // 3072

DEVI u16 f2bf(float f) {                  // RNE f32->bf16 (finite inputs)
  uint32_t u = __builtin_bit_cast(uint32_t, f);
  return (u16)((u + 0x7fffu + ((u >> 16) & 1u)) >> 16);
}
DEVI float bf2f(u16 h) { return __builtin_bit_cast(float, (uint32_t)h << 16); }

DEVI void gll16(const void* g, void* l) { // 16B global -> LDS direct
  __builtin_amdgcn_global_load_lds(
      (const __attribute__((address_space(1))) uint32_t*)g,
      (__attribute__((address_space(3))) uint32_t*)l, 16, 0, 0);
}

// ---------------- f32 -> bf16 convert, 8 elems/thread ----------------
__global__ __launch_bounds__(256) void cvt_kernel(const float* __restrict__ in,
                                                  u16* __restrict__ out, int n8) {
  int idx = blockIdx.x * 256 + threadIdx.x;
  int stride = gridDim.x * 256;
  for (int i = idx; i < n8; i += stride) {
    const float4* p = reinterpret_cast<const float4*>(in) + (size_t)i * 2;
    float4 a = p[0], b = p[1];
    u16x8 v;
    v[0] = f2bf(a.x); v[1] = f2bf(a.y); v[2] = f2bf(a.z); v[3] = f2bf(a.w);
    v[4] = f2bf(b.x); v[5] = f2bf(b.y); v[6] = f2bf(b.z); v[7] = f2bf(b.w);
    reinterpret_cast<u16x8*>(out)[i] = v;
  }
}

// ---------------- C[m,n] = sum_k A[m,k] * B[n,k]  (both row-major, bf16) ---
template <bool OUT_BF16>
__global__ __launch_bounds__(256) void gemm_bt_kernel(
    const u16* __restrict__ A, const u16* __restrict__ B, void* __restrict__ Cv,
    int M, int N, int K) {
  constexpr int BM = 128, BN = 128, BK = 32;
  __shared__ __align__(16) u16 As[2][BM * BK];
  __shared__ __align__(16) u16 Bs[2][BN * BK];
  const int tid  = threadIdx.x;
  const int lane = tid & 63;
  const int wid  = tid >> 6;
  const int bm = blockIdx.x * BM;
  const int bn = blockIdx.y * BN;
  const int wm = (wid >> 1) * 64;
  const int wn = (wid & 1) * 64;
  const int fr = lane & 15, fg = lane >> 4;

  const f32x4 fzero = {0.f, 0.f, 0.f, 0.f};
  f32x4 acc[4][4];
#pragma unroll
  for (int m = 0; m < 4; m++)
#pragma unroll
    for (int n = 0; n < 4; n++) acc[m][n] = fzero;

  auto stage = [&](int buf, int k0) {
#pragma unroll
    for (int i = 0; i < 2; i++) {
      int e = i * 256 + tid;  // 8-elem group: row e>>2, col (e&3)*8
      gll16(A + (size_t)(bm + (e >> 2)) * K + (k0 + (e & 3) * 8), &As[buf][e * 8]);
    }
#pragma unroll
    for (int i = 0; i < 2; i++) {
      int e = i * 256 + tid;
      gll16(B + (size_t)(bn + (e >> 2)) * K + (k0 + (e & 3) * 8), &Bs[buf][e * 8]);
    }
  };

  stage(0, 0);
  __syncthreads();
  const int nt = K / BK;
  for (int t = 0; t < nt; ++t) {
    int cur = t & 1;
    if (t + 1 < nt) stage(cur ^ 1, (t + 1) * BK);
    bf16x8 af[4], bfv[4];
#pragma unroll
    for (int m = 0; m < 4; m++)
      af[m] = *reinterpret_cast<const bf16x8*>(&As[cur][(wm + m * 16 + fr) * BK + fg * 8]);
#pragma unroll
    for (int n = 0; n < 4; n++)
      bfv[n] = *reinterpret_cast<const bf16x8*>(&Bs[cur][(wn + n * 16 + fr) * BK + fg * 8]);
#pragma unroll
    for (int m = 0; m < 4; m++)
#pragma unroll
      for (int n = 0; n < 4; n++)
        acc[m][n] = __builtin_amdgcn_mfma_f32_16x16x32_bf16(af[m], bfv[n], acc[m][n], 0, 0, 0);
    __syncthreads();
  }

#pragma unroll
  for (int m = 0; m < 4; m++)
#pragma unroll
    for (int n = 0; n < 4; n++)
#pragma unroll
      for (int j = 0; j < 4; j++) {
        size_t row = bm + wm + m * 16 + fg * 4 + j;
        size_t col = bn + wn + n * 16 + fr;
        if constexpr (OUT_BF16)
          reinterpret_cast<u16*>(Cv)[row * N + col] = f2bf(acc[m][n][j]);
        else
          reinterpret_cast<float*>(Cv)[row * N + col] = acc[m][n][j];
      }
}

// ---------------- fused RMSNorm + RoPE; one wave per (token, head-slot) ----
__global__ __launch_bounds__(256) void rmsrope_kernel(
    const u16* __restrict__ qkv, const float* __restrict__ cosb,
    const float* __restrict__ sinb, const float* __restrict__ qw,
    const float* __restrict__ kw, u16* __restrict__ Q, u16* __restrict__ K) {
  int gw   = blockIdx.x * 4 + (threadIdx.x >> 6);
  int lane = threadIdx.x & 63;
  int tok  = gw / 20;
  int slot = gw - tok * 20;
  if (tok >= TOK) return;
  int b = tok >> 11, s = tok & (S_ - 1);
  const u16* src = qkv + (size_t)tok * OQKV + slot * HD_;
  float x0 = bf2f(src[lane]);
  float x1 = bf2f(src[lane + 64]);
  float ss = x0 * x0 + x1 * x1;
#pragma unroll
  for (int m = 1; m < 64; m <<= 1) ss += __shfl_xor(ss, m, 64);
  float r = rsqrtf(ss * (1.0f / 128.0f) + 1e-6f);
  const float* w = (slot < 16) ? qw : kw;
  x0 *= r * w[lane];
  x1 *= r * w[lane + 64];
  float c  = cosb[(size_t)tok * 64 + lane];
  float sn = sinb[(size_t)tok * 64 + lane];
  float partner = __shfl_xor(x0, 32, 64);
  float rot = (lane < 32) ? -partner : partner;
  x0 = x0 * c + rot * sn;
  u16* dst;
  if (slot < 16) dst = Q + (((size_t)b * NH_ + slot) * S_ + s) * HD_;
  else           dst = K + (((size_t)b * NKV_ + (slot - 16)) * S_ + s) * HD_;
  dst[lane]      = f2bf(x0);
  dst[lane + 64] = f2bf(x1);
}

// ---------------- flash attention v3: 8 waves x 32 q-rows, 32x32x16 MFMA ---
// Swapped QK^T: S^T = mfma(K,Q) -> lane holds P[kv][q=lane&31] in regs.
// No max tracking needed: |S*scale| <= sqrt(128) after RMSNorm.
// K in LDS (chunk XOR swizzle, staged via global_load_lds with pre-swizzled
// source). V in LDS TRANSPOSED: Vt[128 d][64 kv], chunk XOR swizzle,
// reg-staged transpose write; PV B-frags are plain ds_read_b128.
// P cross-half exchange via __shfl_xor(.,32) (verified primitive).
__global__ __launch_bounds__(512, 2) void attn_kernel(
    const u16* __restrict__ Q, const u16* __restrict__ K,
    const u16* __restrict__ QKVb, u16* __restrict__ O) {
  __shared__ __align__(16) u16 Ks[2][64 * 128];
  __shared__ __align__(16) u16 Vt[2][128 * 64];
  __shared__ float rs_lds[8][32];
  const int tid  = threadIdx.x;
  const int lane = tid & 63, wid = tid >> 6;
  const int q32 = lane & 31, hi = lane >> 5;
  const int qt = blockIdx.x, bh = blockIdx.y;
  const int b = bh >> 4, h = bh & 15, kvh = h >> 2;

  const u16* Qrow  = Q + ((size_t)(b * NH_ + h) * S_ + qt * 256 + wid * 32 + q32) * HD_;
  const u16* Kbase = K + (size_t)(b * NKV_ + kvh) * S_ * HD_;
  const u16* Vbase = QKVb + (size_t)b * S_ * OQKV + (size_t)(NH_ + NKV_) * HD_ + (size_t)kvh * HD_;

  // Q fragments (B-operand): qf[m] = Q[q=q32][d = m*16 + hi*8 .. +8]
  bf16x8 qf[8];
#pragma unroll
  for (int m = 0; m < 8; m++)
    qf[m] = *reinterpret_cast<const bf16x8*>(Qrow + m * 16 + hi * 8);

  f32x16 acc[4];
#pragma unroll
  for (int n = 0; n < 4; n++)
#pragma unroll
    for (int r = 0; r < 16; r++) acc[n][r] = 0.f;

  float rs = 0.f;
  const float scale = 0.08838834764831845f;  // 1/sqrt(128)

  // --- staging helpers ---
  auto stageK = [&](int buf, int kt) {  // gll16 with pre-swizzled source
#pragma unroll
    for (int i = 0; i < 2; i++) {
      int e = i * 512 + tid;
      int krow = e >> 4, ci = e & 15;
      int cs = ci ^ (krow & 15);
      gll16(Kbase + ((size_t)kt * 64 + krow) * HD_ + cs * 8, &Ks[buf][e * 8]);
    }
  };
  // V transpose staging: threads 0..255, each owns 4 kv rows x 8 d cols.
  u16x8 vreg[4];
  auto loadV = [&](int kt) {
    if (tid < 256) {
      int kvb = tid >> 4, db = tid & 15;
#pragma unroll
      for (int i = 0; i < 4; i++)
        vreg[i] = *reinterpret_cast<const u16x8*>(
            Vbase + ((size_t)kt * 64 + kvb * 4 + i) * OQKV + db * 8);
    }
  };
  auto writeV = [&](int buf) {  // Vt[d][kv], chunk ^= (d^(d>>3))&7
    if (tid < 256) {
      int kvb = tid >> 4, db = tid & 15;
#pragma unroll
      for (int j = 0; j < 8; j++) {
        int d = db * 8 + j;
        int sw = (d ^ (d >> 3)) & 7;
        int off = d * 128 + ((((kvb >> 1) ^ sw)) << 4) + ((kvb & 1) << 3);
        short4v wv = {(short)vreg[0][j], (short)vreg[1][j],
                      (short)vreg[2][j], (short)vreg[3][j]};
        *reinterpret_cast<short4v*>(reinterpret_cast<char*>(Vt[buf]) + off) = wv;
      }
    }
  };

  stageK(0, 0);
  loadV(0);
  writeV(0);
  __syncthreads();

  const int NT = S_ / 64;  // 32
  for (int kt = 0; kt < NT; ++kt) {
    const int cur = kt & 1;
    if (kt + 1 < NT) { stageK(cur ^ 1, kt + 1); loadV(kt + 1); }

    // ---- QK^T (swapped): S[kv][q], kv = kb*32 + crow(r,hi) ----
    const u16* kbp = &Ks[cur][(size_t)q32 * 128];
    const int swz = lane & 15;
    unsigned int pa[4][4];
#pragma unroll
    for (int kb = 0; kb < 2; kb++) {
      f32x16 s;
#pragma unroll
      for (int r = 0; r < 16; r++) s[r] = 0.f;
      __builtin_amdgcn_s_setprio(1);
#pragma unroll
      for (int m = 0; m < 8; m++) {
        bf16x8 kf = *reinterpret_cast<const bf16x8*>(
            kbp + kb * 32 * 128 + ((((m * 2 + hi) ^ swz)) << 3));
        s = __builtin_amdgcn_mfma_f32_32x32x16_bf16(kf, qf[m], s, 0, 0, 0);
      }
      __builtin_amdgcn_s_setprio(0);
      float p[16];
#pragma unroll
      for (int r = 0; r < 16; r++) {
        p[r] = __expf(s[r] * scale);
        rs += p[r];
      }
      unsigned int w[8], x[8];
#pragma unroll
      for (int m2 = 0; m2 < 8; m2++)
        w[m2] = (unsigned int)f2bf(p[2 * m2]) | ((unsigned int)f2bf(p[2 * m2 + 1]) << 16);
#pragma unroll
      for (int m2 = 0; m2 < 8; m2++) x[m2] = __shfl_xor(w[m2], 32, 64);
      // A-frag kv order: lane(hi) needs kv = t*16 + hi*8 + {0..7}
#pragma unroll
      for (int tp = 0; tp < 2; tp++) {
        pa[kb * 2 + tp][0] = hi ? x[4 * tp + 2] : w[4 * tp + 0];
        pa[kb * 2 + tp][1] = hi ? x[4 * tp + 3] : w[4 * tp + 1];
        pa[kb * 2 + tp][2] = hi ? w[4 * tp + 2] : x[4 * tp + 0];
        pa[kb * 2 + tp][3] = hi ? w[4 * tp + 3] : x[4 * tp + 1];
      }
    }

    // ---- PV: acc[n] += P[q][kv] * V[kv][d], B-frags from transposed Vt ----
#pragma unroll
    for (int t = 0; t < 4; t++) {
      union { u32x4 u; bf16x8 h; } pf;
      pf.u = (u32x4){pa[t][0], pa[t][1], pa[t][2], pa[t][3]};
      __builtin_amdgcn_s_setprio(1);
#pragma unroll
      for (int n = 0; n < 4; n++) {
        int d = n * 32 + q32;
        int sw = (d ^ (d >> 3)) & 7;
        bf16x8 vf = *reinterpret_cast<const bf16x8*>(
            reinterpret_cast<const char*>(Vt[cur]) + d * 128 + (((t * 2 + hi) ^ sw) << 4));
        acc[n] = __builtin_amdgcn_mfma_f32_32x32x16_bf16(pf.h, vf, acc[n], 0, 0, 0);
      }
      __builtin_amdgcn_s_setprio(0);
    }

    if (kt + 1 < NT) writeV(cur ^ 1);
    __syncthreads();
  }

  // ---- epilogue: denominators + O write ----
  float rtot = rs + __shfl_xor(rs, 32, 64);
  if (lane < 32) rs_lds[wid][q32] = rtot;
  __syncthreads();
  float rinv[16];
#pragma unroll
  for (int r = 0; r < 16; r++)
    rinv[r] = 1.0f / rs_lds[wid][(r & 3) + 8 * (r >> 2) + 4 * hi];

  const int qrow0 = qt * 256 + wid * 32;
  u16* ob = O + ((size_t)b * S_ + qrow0) * HID_ + h * HD_ + q32;
#pragma unroll
  for (int n = 0; n < 4; n++)
#pragma unroll
    for (int r = 0; r < 16; r++) {
      int qr = (r & 3) + 8 * (r >> 2) + 4 * hi;
      ob[(size_t)qr * HID_ + n * 32] = f2bf(acc[n][r] * rinv[r]);
    }
}

// ---------------------------------------------------------------------------
extern "C" void kernel_launch(void* const* d_in, const int* in_sizes, int n_in,
                              void* d_out, int out_size, void* d_ws, size_t ws_size,
                              hipStream_t stream) {
  (void)in_sizes; (void)n_in; (void)out_size; (void)ws_size;
  const float* hs   = (const float*)d_in[0];
  const float* cosb = (const float*)d_in[1];
  const float* sinb = (const float*)d_in[2];
  const float* wqkv = (const float*)d_in[3];
  const float* qw   = (const float*)d_in[4];
  const float* kw   = (const float*)d_in[5];
  const float* wd   = (const float*)d_in[6];
  float* out = (float*)d_out;
  char* ws = (char*)d_ws;
  constexpr size_t MB = 1048576;
  u16* Xb    = (u16*)(ws + 0 * MB);    // 16 MB  X bf16        [4096][2048]
  u16* Wqkvb = (u16*)(ws + 16 * MB);   // 12 MB  w_qkv bf16    [3072][2048]
  u16* Wdb   = (u16*)(ws + 28 * MB);   //  8 MB  w_dense bf16  [2048][2048]
  u16* QKVb  = (u16*)(ws + 36 * MB);   // 24 MB  qkv bf16      [4096][3072]
  u16* Qb    = (u16*)(ws + 60 * MB);   // 16 MB  Q             [B][NH][S][HD]
  u16* Kb    = (u16*)(ws + 76 * MB);   //  4 MB  K             [B][NKV][S][HD]
  u16* Ob    = (u16*)(ws + 80 * MB);   // 16 MB  attn out      [B][S][NH*HD]

  cvt_kernel<<<2048, 256, 0, stream>>>(hs, Xb, TOK * HID_ / 8);
  cvt_kernel<<<2048, 256, 0, stream>>>(wqkv, Wqkvb, OQKV * HID_ / 8);
  cvt_kernel<<<1024, 256, 0, stream>>>(wd, Wdb, HID_ * HID_ / 8);

  gemm_bt_kernel<true><<<dim3(TOK / 128, OQKV / 128), 256, 0, stream>>>(
      Xb, Wqkvb, QKVb, TOK, OQKV, HID_);

  rmsrope_kernel<<<TOK * 20 / 4, 256, 0, stream>>>(QKVb, cosb, sinb, qw, kw, Qb, Kb);

  attn_kernel<<<dim3(S_ / 256, B_ * NH_), 512, 0, stream>>>(Qb, Kb, QKVb, Ob);

  gemm_bt_kernel<false><<<dim3(TOK / 128, HID_ / 128), 256, 0, stream>>>(
      Ob, Wdb, out, TOK, HID_, HID_);
}